// Round 2
// baseline (1242.460 us; speedup 1.0000x reference)
//
#include <hip/hip_runtime.h>
#include <hip/hip_bf16.h>
#include <math.h>

// ---------------- CSR build ----------------

__global__ void count_kernel(const int* __restrict__ ei, int* __restrict__ cnt, int E) {
    int e = blockIdx.x * blockDim.x + threadIdx.x;
    if (e < E) atomicAdd(&cnt[ei[E + e]], 1);
}

__global__ void dinv_kernel(const int* __restrict__ cnt, float* __restrict__ dinv, int N) {
    int v = blockIdx.x * blockDim.x + threadIdx.x;
    if (v < N) dinv[v] = rsqrtf((float)(cnt[v] + 1));   // +1 for self-loop
}

// block-level scan: 256 threads x 4 elems = 1024 per block
__global__ void scan1(const int* __restrict__ cnt, int* __restrict__ rowstart,
                      int* __restrict__ bsum, int N) {
    __shared__ int sdata[256];
    int base = blockIdx.x * 1024;
    int t = threadIdx.x;
    int v[4]; int s = 0;
#pragma unroll
    for (int i = 0; i < 4; i++) {
        int idx = base + t * 4 + i;
        v[i] = (idx < N) ? cnt[idx] : 0;
        s += v[i];
    }
    sdata[t] = s;
    __syncthreads();
    for (int off = 1; off < 256; off <<= 1) {
        int val = (t >= off) ? sdata[t - off] : 0;
        __syncthreads();
        sdata[t] += val;
        __syncthreads();
    }
    int excl = (t > 0) ? sdata[t - 1] : 0;
    if (t == 255) bsum[blockIdx.x] = sdata[255];
    int run = excl;
#pragma unroll
    for (int i = 0; i < 4; i++) {
        int idx = base + t * 4 + i;
        if (idx < N) rowstart[idx] = run;
        run += v[i];
    }
}

__global__ void scan2(int* __restrict__ bsum, int nb, int* __restrict__ rowstart, int N, int E) {
    if (threadIdx.x == 0 && blockIdx.x == 0) {
        int acc = 0;
        for (int i = 0; i < nb; i++) { int t = bsum[i]; bsum[i] = acc; acc += t; }
        rowstart[N] = E;
    }
}

__global__ void scan3(int* __restrict__ rowstart, const int* __restrict__ bsum, int N) {
    int i = blockIdx.x * blockDim.x + threadIdx.x;
    if (i < N) rowstart[i] += bsum[i >> 10];
}

__global__ void scatter_kernel(const int* __restrict__ ei, const int* __restrict__ rowstart,
                               int* __restrict__ fill, int* __restrict__ srcs, int E) {
    int e = blockIdx.x * blockDim.x + threadIdx.x;
    if (e < E) {
        int s = ei[e], d = ei[E + e];
        int p = rowstart[d] + atomicAdd(&fill[d], 1);
        srcs[p] = s;
    }
}

// ---------------- GEMM: H = X @ W  (X:[N,128], W:[128,128]) ----------------
__global__ __launch_bounds__(256) void gemm_nn_128(const float* __restrict__ X,
                                                   const float* __restrict__ W,
                                                   float* __restrict__ H, int N) {
    __shared__ float Ws[128 * 128];   // [k][c]  64KB
    __shared__ float Xs[32 * 128];    // [r][k]  16KB
    int t = threadIdx.x;
    int row0 = blockIdx.x * 32;
    for (int i = t; i < 128 * 128; i += 256) Ws[i] = W[i];
    for (int i = t; i < 32 * 128; i += 256) {
        int r = i >> 7, k = i & 127;
        int gr = row0 + r;
        Xs[i] = (gr < N) ? X[gr * 128 + k] : 0.f;
    }
    __syncthreads();
    int c0 = (t & 31) * 4;
    int r0 = (t >> 5) * 4;
    float acc[4][4] = {};
    for (int k = 0; k < 128; k++) {
        float wv0 = Ws[k * 128 + c0 + 0];
        float wv1 = Ws[k * 128 + c0 + 1];
        float wv2 = Ws[k * 128 + c0 + 2];
        float wv3 = Ws[k * 128 + c0 + 3];
#pragma unroll
        for (int i = 0; i < 4; i++) {
            float xv = Xs[(r0 + i) * 128 + k];
            acc[i][0] += xv * wv0;
            acc[i][1] += xv * wv1;
            acc[i][2] += xv * wv2;
            acc[i][3] += xv * wv3;
        }
    }
#pragma unroll
    for (int i = 0; i < 4; i++) {
        int gr = row0 + r0 + i;
        if (gr < N) {
            float4 o = make_float4(acc[i][0], acc[i][1], acc[i][2], acc[i][3]);
            *(float4*)&H[gr * 128 + c0] = o;
        }
    }
}

// ---------------- GEMM: H = X @ W3 (X:[N,128], W3:[128,40]) ----------------
__global__ __launch_bounds__(320) void gemm_nn_40(const float* __restrict__ X,
                                                  const float* __restrict__ W,
                                                  float* __restrict__ H, int N) {
    __shared__ float Ws[128 * 40];    // ~20KB
    __shared__ float Xs[64 * 128];    // 32KB
    int t = threadIdx.x;              // 320 threads
    int row0 = blockIdx.x * 64;
    for (int i = t; i < 128 * 40; i += 320) Ws[i] = W[i];
    for (int i = t; i < 64 * 128; i += 320) {
        int r = i >> 7, k = i & 127;
        int gr = row0 + r;
        Xs[i] = (gr < N) ? X[gr * 128 + k] : 0.f;
    }
    __syncthreads();
    int c  = t % 40;
    int rg = t / 40;                  // 0..7
    float acc[8] = {};
    for (int k = 0; k < 128; k++) {
        float wv = Ws[k * 40 + c];
#pragma unroll
        for (int i = 0; i < 8; i++) acc[i] += Xs[(rg * 8 + i) * 128 + k] * wv;
    }
#pragma unroll
    for (int i = 0; i < 8; i++) {
        int gr = row0 + rg * 8 + i;
        if (gr < N) H[gr * 40 + c] = acc[i];
    }
}

// ---------------- Aggregation (width 128): out[v] = relu?(dinv[v]*(sum_s h[s]*dinv[s] + h[v]*dinv[v]) + b)
__global__ __launch_bounds__(256) void agg128(const float* __restrict__ Hpre,
                                              const int* __restrict__ rowstart,
                                              const int* __restrict__ srcs,
                                              const float* __restrict__ dinv,
                                              const float* __restrict__ b,
                                              float* __restrict__ Hout, int N, int doRelu) {
    int v = blockIdx.x * 2 + (threadIdx.x >> 7);
    int f = threadIdx.x & 127;
    if (v >= N) return;
    int p0 = rowstart[v], p1 = rowstart[v + 1];
    float dv = dinv[v];
    float acc = Hpre[v * 128 + f] * dv;
    for (int p = p0; p < p1; p++) {
        int s = srcs[p];
        acc += Hpre[s * 128 + f] * dinv[s];
    }
    float val = acc * dv + b[f];
    Hout[v * 128 + f] = doRelu ? fmaxf(val, 0.f) : val;
}

// ---------------- Aggregation (width 40) + bias + log_softmax fused ----------------
__global__ __launch_bounds__(256) void agg40_lsm(const float* __restrict__ Hpre,
                                                 const int* __restrict__ rowstart,
                                                 const int* __restrict__ srcs,
                                                 const float* __restrict__ dinv,
                                                 const float* __restrict__ b3,
                                                 float* __restrict__ Out, int N) {
    int v = blockIdx.x * 4 + (threadIdx.x >> 6);
    int lane = threadIdx.x & 63;
    if (v >= N) return;
    bool active = lane < 40;
    int p0 = rowstart[v], p1 = rowstart[v + 1];
    float dv = dinv[v];
    float acc = 0.f;
    if (active) acc = Hpre[v * 40 + lane] * dv;
    for (int p = p0; p < p1; p++) {
        int s = srcs[p];
        float ds = dinv[s];
        if (active) acc += Hpre[s * 40 + lane] * ds;
    }
    float val = active ? (acc * dv + b3[lane]) : -INFINITY;
    float m = val;
    for (int off = 32; off; off >>= 1) m = fmaxf(m, __shfl_xor(m, off));
    float ex = active ? expf(val - m) : 0.f;
    float sum = ex;
    for (int off = 32; off; off >>= 1) sum += __shfl_xor(sum, off);
    if (active) Out[v * 40 + lane] = val - m - logf(sum);
}

// ---------------- launcher ----------------
extern "C" void kernel_launch(void* const* d_in, const int* in_sizes, int n_in,
                              void* d_out, int out_size, void* d_ws, size_t ws_size,
                              hipStream_t stream) {
    const float* x  = (const float*)d_in[0];
    const int*   ei = (const int*)d_in[1];
    const float* W1 = (const float*)d_in[2];
    const float* b1 = (const float*)d_in[3];
    const float* W2 = (const float*)d_in[4];
    const float* b2 = (const float*)d_in[5];
    const float* W3 = (const float*)d_in[6];
    const float* b3 = (const float*)d_in[7];
    float* out = (float*)d_out;

    const int N = in_sizes[0] / 128;
    const int E = in_sizes[1] / 2;

    auto align = [](size_t v) { return (v + 255) & ~(size_t)255; };
    char* w = (char*)d_ws;
    size_t off = 0;
    float* hA = (float*)(w + off); off += align((size_t)N * 128 * 4);
    float* hB = (float*)(w + off); off += align((size_t)N * 128 * 4);
    int* cnt  = (int*)(w + off);   off += align((size_t)N * 4);
    int* fill = (int*)(w + off);   off += align((size_t)N * 4);
    int* rowstart = (int*)(w + off); off += align((size_t)(N + 1) * 4);
    float* dinv = (float*)(w + off); off += align((size_t)N * 4);
    int* srcs = (int*)(w + off);   off += align((size_t)E * 4);
    int* bsum = (int*)(w + off);   off += align((size_t)1024 * 4);

    hipMemsetAsync(cnt, 0, (size_t)N * 4, stream);
    hipMemsetAsync(fill, 0, (size_t)N * 4, stream);

    int nb = (N + 1023) / 1024;
    count_kernel<<<(E + 255) / 256, 256, 0, stream>>>(ei, cnt, E);
    dinv_kernel<<<(N + 255) / 256, 256, 0, stream>>>(cnt, dinv, N);
    scan1<<<nb, 256, 0, stream>>>(cnt, rowstart, bsum, N);
    scan2<<<1, 64, 0, stream>>>(bsum, nb, rowstart, N, E);
    scan3<<<(N + 255) / 256, 256, 0, stream>>>(rowstart, bsum, N);
    scatter_kernel<<<(E + 255) / 256, 256, 0, stream>>>(ei, rowstart, fill, srcs, E);

    // layer 1
    gemm_nn_128<<<(N + 31) / 32, 256, 0, stream>>>(x, W1, hA, N);
    agg128<<<(N + 1) / 2, 256, 0, stream>>>(hA, rowstart, srcs, dinv, b1, hB, N, 1);
    // layer 2
    gemm_nn_128<<<(N + 31) / 32, 256, 0, stream>>>(hB, W2, hA, N);
    agg128<<<(N + 1) / 2, 256, 0, stream>>>(hA, rowstart, srcs, dinv, b2, hB, N, 1);
    // layer 3 + log_softmax
    gemm_nn_40<<<(N + 63) / 64, 320, 0, stream>>>(hB, W3, hA, N);
    agg40_lsm<<<(N + 3) / 4, 256, 0, stream>>>(hA, rowstart, srcs, dinv, b3, out, N);
}

// Round 3
// 688.325 us; speedup vs baseline: 1.8050x; 1.8050x over previous
//
#include <hip/hip_runtime.h>
#include <hip/hip_bf16.h>
#include <math.h>

__device__ __forceinline__ float bf2f(unsigned short u) {
    return __uint_as_float(((unsigned)u) << 16);
}
__device__ __forceinline__ unsigned short f2bf(float f) {
    unsigned u = __float_as_uint(f);
    return (unsigned short)((u + 0x7FFF + ((u >> 16) & 1)) >> 16);
}

// ---------------- CSR build ----------------

__global__ void count_kernel(const int* __restrict__ ei, int* __restrict__ cnt, int E) {
    int e = blockIdx.x * blockDim.x + threadIdx.x;
    if (e < E) atomicAdd(&cnt[ei[E + e]], 1);
}

__global__ void dinv_kernel(const int* __restrict__ cnt, float* __restrict__ dinv, int N) {
    int v = blockIdx.x * blockDim.x + threadIdx.x;
    if (v < N) dinv[v] = rsqrtf((float)(cnt[v] + 1));   // +1 for self-loop
}

__global__ void scan1(const int* __restrict__ cnt, int* __restrict__ rowstart,
                      int* __restrict__ bsum, int N) {
    __shared__ int sdata[256];
    int base = blockIdx.x * 1024;
    int t = threadIdx.x;
    int v[4]; int s = 0;
#pragma unroll
    for (int i = 0; i < 4; i++) {
        int idx = base + t * 4 + i;
        v[i] = (idx < N) ? cnt[idx] : 0;
        s += v[i];
    }
    sdata[t] = s;
    __syncthreads();
    for (int off = 1; off < 256; off <<= 1) {
        int val = (t >= off) ? sdata[t - off] : 0;
        __syncthreads();
        sdata[t] += val;
        __syncthreads();
    }
    int excl = (t > 0) ? sdata[t - 1] : 0;
    if (t == 255) bsum[blockIdx.x] = sdata[255];
    int run = excl;
#pragma unroll
    for (int i = 0; i < 4; i++) {
        int idx = base + t * 4 + i;
        if (idx < N) rowstart[idx] = run;
        run += v[i];
    }
}

__global__ void scan2(int* __restrict__ bsum, int nb, int* __restrict__ rowstart, int N, int E) {
    if (threadIdx.x == 0 && blockIdx.x == 0) {
        int acc = 0;
        for (int i = 0; i < nb; i++) { int t = bsum[i]; bsum[i] = acc; acc += t; }
        rowstart[N] = E;
    }
}

__global__ void scan3(int* __restrict__ rowstart, const int* __restrict__ bsum, int N) {
    int i = blockIdx.x * blockDim.x + threadIdx.x;
    if (i < N) rowstart[i] += bsum[i >> 10];
}

__global__ void scatter_kernel(const int* __restrict__ ei, const int* __restrict__ rowstart,
                               int* __restrict__ fill, int* __restrict__ srcs, int E) {
    int e = blockIdx.x * blockDim.x + threadIdx.x;
    if (e < E) {
        int s = ei[e], d = ei[E + e];
        int p = rowstart[d] + atomicAdd(&fill[d], 1);
        srcs[p] = s;
    }
}

// ---------------- GEMM: H = (X @ W) * dinv[row], output bf16 [N,128] ----------------
__global__ __launch_bounds__(256) void gemm128_bf16s(const float* __restrict__ X,
                                                     const float* __restrict__ W,
                                                     const float* __restrict__ dinv,
                                                     unsigned short* __restrict__ H, int N) {
    __shared__ float Ws[128 * 128];   // [k][c]
    __shared__ float Xs[32 * 128];    // [r][k]
    int t = threadIdx.x;
    int row0 = blockIdx.x * 32;
    for (int i = t; i < 128 * 128 / 4; i += 256) ((float4*)Ws)[i] = ((const float4*)W)[i];
    for (int i = t; i < 32 * 128 / 4; i += 256) {
        int r = i >> 5, k4 = i & 31;
        int gr = row0 + r;
        ((float4*)Xs)[i] = (gr < N) ? ((const float4*)X)[(size_t)gr * 32 + k4]
                                    : make_float4(0.f, 0.f, 0.f, 0.f);
    }
    __syncthreads();
    int c0 = (t & 31) * 4;
    int r0 = (t >> 5) * 4;
    float acc[4][4] = {};
    for (int k = 0; k < 128; k += 4) {
        float4 w0 = *(float4*)&Ws[(k + 0) * 128 + c0];
        float4 w1 = *(float4*)&Ws[(k + 1) * 128 + c0];
        float4 w2 = *(float4*)&Ws[(k + 2) * 128 + c0];
        float4 w3 = *(float4*)&Ws[(k + 3) * 128 + c0];
#pragma unroll
        for (int i = 0; i < 4; i++) {
            float4 xv = *(float4*)&Xs[(r0 + i) * 128 + k];
            acc[i][0] += xv.x * w0.x + xv.y * w1.x + xv.z * w2.x + xv.w * w3.x;
            acc[i][1] += xv.x * w0.y + xv.y * w1.y + xv.z * w2.y + xv.w * w3.y;
            acc[i][2] += xv.x * w0.z + xv.y * w1.z + xv.z * w2.z + xv.w * w3.z;
            acc[i][3] += xv.x * w0.w + xv.y * w1.w + xv.z * w2.w + xv.w * w3.w;
        }
    }
#pragma unroll
    for (int i = 0; i < 4; i++) {
        int gr = row0 + r0 + i;
        if (gr < N) {
            float dv = dinv[gr];
            ushort4 o;
            o.x = f2bf(acc[i][0] * dv); o.y = f2bf(acc[i][1] * dv);
            o.z = f2bf(acc[i][2] * dv); o.w = f2bf(acc[i][3] * dv);
            *(ushort4*)&H[(size_t)gr * 128 + c0] = o;
        }
    }
}

// ---------------- Aggregation over bf16 pre-scaled rows ----------------
// Input rows hs[v] = h[v]*dinv[v] (bf16). acc = hs[v] + sum_nbr hs[s].
// MODE 0: out fp32 = relu(acc*dv + b)          (layer 1)
// MODE 1: out bf16 = relu(acc*dv + b) * dv     (layer 2, pre-scaled for next agg)
// MODE 2: out fp32 = acc*dv                    (layer 3 pre-GEMM)
template<int MODE>
__global__ __launch_bounds__(256) void agg128_g(const ushort4* __restrict__ Hp,
                                                const int* __restrict__ rowstart,
                                                const int* __restrict__ srcs,
                                                const float* __restrict__ dinv,
                                                const float* __restrict__ bias,
                                                void* __restrict__ Hout, int N) {
    int r = blockIdx.x * 8 + (threadIdx.x >> 5);
    if (r >= N) return;
    int lane = threadIdx.x & 31;
    int p0 = rowstart[r], p1 = rowstart[r + 1];
    ushort4 sv = Hp[(size_t)r * 32 + lane];
    float a0 = bf2f(sv.x), a1 = bf2f(sv.y), a2 = bf2f(sv.z), a3 = bf2f(sv.w);
    int p = p0;
    for (; p + 4 <= p1; p += 4) {
        int s0 = srcs[p], s1 = srcs[p + 1], s2 = srcs[p + 2], s3 = srcs[p + 3];
        ushort4 v0 = Hp[(size_t)s0 * 32 + lane];
        ushort4 v1 = Hp[(size_t)s1 * 32 + lane];
        ushort4 v2 = Hp[(size_t)s2 * 32 + lane];
        ushort4 v3 = Hp[(size_t)s3 * 32 + lane];
        a0 += bf2f(v0.x) + bf2f(v1.x) + bf2f(v2.x) + bf2f(v3.x);
        a1 += bf2f(v0.y) + bf2f(v1.y) + bf2f(v2.y) + bf2f(v3.y);
        a2 += bf2f(v0.z) + bf2f(v1.z) + bf2f(v2.z) + bf2f(v3.z);
        a3 += bf2f(v0.w) + bf2f(v1.w) + bf2f(v2.w) + bf2f(v3.w);
    }
    for (; p < p1; ++p) {
        int s = srcs[p];
        ushort4 v = Hp[(size_t)s * 32 + lane];
        a0 += bf2f(v.x); a1 += bf2f(v.y); a2 += bf2f(v.z); a3 += bf2f(v.w);
    }
    float dv = dinv[r];
    if (MODE == 0) {
        float o0 = fmaxf(a0 * dv + bias[lane * 4 + 0], 0.f);
        float o1 = fmaxf(a1 * dv + bias[lane * 4 + 1], 0.f);
        float o2 = fmaxf(a2 * dv + bias[lane * 4 + 2], 0.f);
        float o3 = fmaxf(a3 * dv + bias[lane * 4 + 3], 0.f);
        ((float4*)Hout)[(size_t)r * 32 + lane] = make_float4(o0, o1, o2, o3);
    } else if (MODE == 1) {
        float o0 = fmaxf(a0 * dv + bias[lane * 4 + 0], 0.f) * dv;
        float o1 = fmaxf(a1 * dv + bias[lane * 4 + 1], 0.f) * dv;
        float o2 = fmaxf(a2 * dv + bias[lane * 4 + 2], 0.f) * dv;
        float o3 = fmaxf(a3 * dv + bias[lane * 4 + 3], 0.f) * dv;
        ushort4 o; o.x = f2bf(o0); o.y = f2bf(o1); o.z = f2bf(o2); o.w = f2bf(o3);
        ((ushort4*)Hout)[(size_t)r * 32 + lane] = o;
    } else {
        ((float4*)Hout)[(size_t)r * 32 + lane] =
            make_float4(a0 * dv, a1 * dv, a2 * dv, a3 * dv);
    }
}

// ---------------- Fused: Out = log_softmax(T @ W3 + b3), T fp32 [N,128] ----------------
__global__ __launch_bounds__(320) void gemm40_lsm(const float* __restrict__ X,
                                                  const float* __restrict__ W,
                                                  const float* __restrict__ b3,
                                                  float* __restrict__ Out, int N) {
    __shared__ float Ws[128 * 40];
    __shared__ float Xs[64 * 128];
    __shared__ float S[64 * 41];
    __shared__ float mrow[64], lrow[64];
    int t = threadIdx.x;              // 320 threads
    int row0 = blockIdx.x * 64;
    for (int i = t; i < 128 * 40; i += 320) Ws[i] = W[i];
    for (int i = t; i < 64 * 128 / 4; i += 320) {
        int r = i >> 5, k4 = i & 31;
        int gr = row0 + r;
        ((float4*)Xs)[i] = (gr < N) ? ((const float4*)X)[(size_t)gr * 32 + k4]
                                    : make_float4(0.f, 0.f, 0.f, 0.f);
    }
    __syncthreads();
    int c  = t % 40;
    int rg = t / 40;                  // 0..7
    float acc[8] = {};
    for (int k = 0; k < 128; k += 4) {
        float wv0 = Ws[(k + 0) * 40 + c];
        float wv1 = Ws[(k + 1) * 40 + c];
        float wv2 = Ws[(k + 2) * 40 + c];
        float wv3 = Ws[(k + 3) * 40 + c];
#pragma unroll
        for (int i = 0; i < 8; i++) {
            float4 xv = *(float4*)&Xs[(rg * 8 + i) * 128 + k];
            acc[i] += xv.x * wv0 + xv.y * wv1 + xv.z * wv2 + xv.w * wv3;
        }
    }
#pragma unroll
    for (int i = 0; i < 8; i++) S[(rg * 8 + i) * 41 + c] = acc[i] + b3[c];
    __syncthreads();
    if (t < 64) {
        float m = -INFINITY;
        for (int c2 = 0; c2 < 40; c2++) m = fmaxf(m, S[t * 41 + c2]);
        float sum = 0.f;
        for (int c2 = 0; c2 < 40; c2++) sum += expf(S[t * 41 + c2] - m);
        mrow[t] = m; lrow[t] = logf(sum);
    }
    __syncthreads();
    for (int idx = t; idx < 64 * 40; idx += 320) {
        int r = idx / 40, c2 = idx % 40;
        int gr = row0 + r;
        if (gr < N) Out[(size_t)gr * 40 + c2] = S[r * 41 + c2] - mrow[r] - lrow[r];
    }
}

// ---------------- launcher ----------------
extern "C" void kernel_launch(void* const* d_in, const int* in_sizes, int n_in,
                              void* d_out, int out_size, void* d_ws, size_t ws_size,
                              hipStream_t stream) {
    const float* x  = (const float*)d_in[0];
    const int*   ei = (const int*)d_in[1];
    const float* W1 = (const float*)d_in[2];
    const float* b1 = (const float*)d_in[3];
    const float* W2 = (const float*)d_in[4];
    const float* b2 = (const float*)d_in[5];
    const float* W3 = (const float*)d_in[6];
    const float* b3 = (const float*)d_in[7];
    float* out = (float*)d_out;

    const int N = in_sizes[0] / 128;
    const int E = in_sizes[1] / 2;

    auto align = [](size_t v) { return (v + 255) & ~(size_t)255; };
    char* w = (char*)d_ws;
    size_t off = 0;
    float* bufA = (float*)(w + off);          off += align((size_t)N * 128 * 4);  // fp32 h
    unsigned short* buf1 = (unsigned short*)(w + off); off += align((size_t)N * 128 * 2);
    unsigned short* buf2 = (unsigned short*)(w + off); off += align((size_t)N * 128 * 2);
    int* cnt  = (int*)(w + off);   off += align((size_t)N * 4);
    int* fill = (int*)(w + off);   off += align((size_t)N * 4);
    int* rowstart = (int*)(w + off); off += align((size_t)(N + 1) * 4);
    float* dinv = (float*)(w + off); off += align((size_t)N * 4);
    int* srcs = (int*)(w + off);   off += align((size_t)E * 4);
    int* bsum = (int*)(w + off);   off += align((size_t)1024 * 4);

    hipMemsetAsync(cnt, 0, (size_t)N * 4, stream);
    hipMemsetAsync(fill, 0, (size_t)N * 4, stream);

    int nb = (N + 1023) / 1024;
    count_kernel<<<(E + 255) / 256, 256, 0, stream>>>(ei, cnt, E);
    dinv_kernel<<<(N + 255) / 256, 256, 0, stream>>>(cnt, dinv, N);
    scan1<<<nb, 256, 0, stream>>>(cnt, rowstart, bsum, N);
    scan2<<<1, 64, 0, stream>>>(bsum, nb, rowstart, N, E);
    scan3<<<(N + 255) / 256, 256, 0, stream>>>(rowstart, bsum, N);
    scatter_kernel<<<(E + 255) / 256, 256, 0, stream>>>(ei, rowstart, fill, srcs, E);

    int gagg = (N + 7) / 8;
    // layer 1: g1s = (x@W1)*dinv (bf16) -> h1 = relu(agg+b1) fp32
    gemm128_bf16s<<<(N + 31) / 32, 256, 0, stream>>>(x, W1, dinv, buf1, N);
    agg128_g<0><<<gagg, 256, 0, stream>>>((const ushort4*)buf1, rowstart, srcs, dinv, b1, bufA, N);
    // layer 2: g2s = (h1@W2)*dinv (bf16) -> h2s = relu(agg+b2)*dinv (bf16)
    gemm128_bf16s<<<(N + 31) / 32, 256, 0, stream>>>(bufA, W2, dinv, buf1, N);
    agg128_g<1><<<gagg, 256, 0, stream>>>((const ushort4*)buf1, rowstart, srcs, dinv, b2, buf2, N);
    // layer 3: t = agg(h2s)*dv fp32 -> out = log_softmax(t@W3 + b3)
    agg128_g<2><<<gagg, 256, 0, stream>>>((const ushort4*)buf2, rowstart, srcs, dinv, dinv, bufA, N);
    gemm40_lsm<<<(N + 63) / 64, 320, 0, stream>>>(bufA, W3, b3, out, N);
}

// Round 4
// 528.708 us; speedup vs baseline: 2.3500x; 1.3019x over previous
//
#include <hip/hip_runtime.h>
#include <hip/hip_bf16.h>
#include <math.h>

typedef short bf16x8 __attribute__((ext_vector_type(8)));
typedef unsigned short us8 __attribute__((ext_vector_type(8)));
typedef float f32x4 __attribute__((ext_vector_type(4)));

__device__ __forceinline__ float bf2f(unsigned short u) {
    return __uint_as_float(((unsigned)u) << 16);
}
__device__ __forceinline__ unsigned short f2bf(float f) {
    unsigned u = __float_as_uint(f);
    return (unsigned short)((u + 0x7FFF + ((u >> 16) & 1)) >> 16);
}

// ---------------- CSR build ----------------

__global__ void count_kernel(const int* __restrict__ ei, int* __restrict__ cnt, int E) {
    int e = blockIdx.x * blockDim.x + threadIdx.x;
    if (e < E) atomicAdd(&cnt[ei[E + e]], 1);
}

__global__ void dinv_kernel(const int* __restrict__ cnt, float* __restrict__ dinv, int N) {
    int v = blockIdx.x * blockDim.x + threadIdx.x;
    if (v < N) dinv[v] = rsqrtf((float)(cnt[v] + 1));
}

__global__ void scan1(const int* __restrict__ cnt, int* __restrict__ rowstart,
                      int* __restrict__ bsum, int N) {
    __shared__ int sdata[256];
    int base = blockIdx.x * 1024;
    int t = threadIdx.x;
    int v[4]; int s = 0;
#pragma unroll
    for (int i = 0; i < 4; i++) {
        int idx = base + t * 4 + i;
        v[i] = (idx < N) ? cnt[idx] : 0;
        s += v[i];
    }
    sdata[t] = s;
    __syncthreads();
    for (int off = 1; off < 256; off <<= 1) {
        int val = (t >= off) ? sdata[t - off] : 0;
        __syncthreads();
        sdata[t] += val;
        __syncthreads();
    }
    int excl = (t > 0) ? sdata[t - 1] : 0;
    if (t == 255) bsum[blockIdx.x] = sdata[255];
    int run = excl;
#pragma unroll
    for (int i = 0; i < 4; i++) {
        int idx = base + t * 4 + i;
        if (idx < N) rowstart[idx] = run;
        run += v[i];
    }
}

__global__ void scan2(int* __restrict__ bsum, int nb, int* __restrict__ rowstart, int N, int E) {
    if (threadIdx.x == 0 && blockIdx.x == 0) {
        int acc = 0;
        for (int i = 0; i < nb; i++) { int t = bsum[i]; bsum[i] = acc; acc += t; }
        rowstart[N] = E;
    }
}

__global__ void scan3(int* __restrict__ rowstart, const int* __restrict__ bsum, int N) {
    int i = blockIdx.x * blockDim.x + threadIdx.x;
    if (i < N) rowstart[i] += bsum[i >> 10];
}

__global__ void scatter_kernel(const int* __restrict__ ei, const int* __restrict__ rowstart,
                               int* __restrict__ fill, int* __restrict__ srcs, int E) {
    int e = blockIdx.x * blockDim.x + threadIdx.x;
    if (e < E) {
        int s = ei[e], d = ei[E + e];
        int p = rowstart[d] + atomicAdd(&fill[d], 1);
        srcs[p] = s;
    }
}

// ---------------- W transpose: W[K=128][C] fp32 -> WT[C][128] bf16 ----------------
struct TW {
    const float* src[3];
    unsigned short* dst[3];
    int C[3];
};
__global__ __launch_bounds__(256) void transposeW(TW tw) {
    __shared__ float Ts[128 * 128];
    int b = blockIdx.x;
    const float* W = tw.src[b];
    unsigned short* WT = tw.dst[b];
    int C = tw.C[b];
    int t = threadIdx.x;
    for (int i = t; i < 128 * C; i += 256) Ts[i] = W[i];
    __syncthreads();
    for (int i = t; i < C * 128; i += 256) {
        int c = i >> 7, k = i & 127;
        WT[c * 128 + k] = f2bf(Ts[k * C + c]);
    }
}

// ---------------- MFMA GEMM: Hout[r][c] = (X[r][:] @ W[:][c]) * dinv[r], bf16 out
// X: [N][128] (fp32 if FP32IN else bf16). WT: [NCOL][128] bf16. NT = ceil(NCOL/16).
template<int NT, int NCOL, bool FP32IN>
__global__ __launch_bounds__(256) void gemm_mfma(const void* __restrict__ Xin,
                                                 const unsigned short* __restrict__ WT,
                                                 const float* __restrict__ dinv,
                                                 unsigned short* __restrict__ Hout, int N) {
    __shared__ unsigned short Ws[NT * 16 * 128];
    __shared__ unsigned short Xs[64 * 128];
    int t = threadIdx.x;
    int row0 = blockIdx.x * 64;
    // stage WT (swizzled): rows r of WT, 16B slots s
    for (int i = t; i < NT * 16 * 16; i += 256) {
        int r = i >> 4, s = i & 15;
        us8 val = (us8)0;
        if (r < NCOL) val = *(const us8*)&WT[r * 128 + s * 8];
        int byte = (r * 256) + ((s * 16) ^ ((r & 7) << 4));
        *(us8*)((char*)Ws + byte) = val;
    }
    // stage X tile (swizzled, convert if fp32)
    for (int i = t; i < 64 * 16; i += 256) {
        int r = i >> 4, s = i & 15;
        int gr = row0 + r;
        us8 val = (us8)0;
        if (gr < N) {
            if (FP32IN) {
                const float4* Xf = (const float4*)Xin;
                float4 f0 = Xf[(size_t)gr * 32 + s * 2];
                float4 f1 = Xf[(size_t)gr * 32 + s * 2 + 1];
                val[0] = f2bf(f0.x); val[1] = f2bf(f0.y); val[2] = f2bf(f0.z); val[3] = f2bf(f0.w);
                val[4] = f2bf(f1.x); val[5] = f2bf(f1.y); val[6] = f2bf(f1.z); val[7] = f2bf(f1.w);
            } else {
                const unsigned short* Xh = (const unsigned short*)Xin;
                val = *(const us8*)&Xh[(size_t)gr * 128 + s * 8];
            }
        }
        int byte = (r * 256) + ((s * 16) ^ ((r & 7) << 4));
        *(us8*)((char*)Xs + byte) = val;
    }
    __syncthreads();

    int wid = t >> 6, lane = t & 63;
    int arow = wid * 16 + (lane & 15);
    f32x4 acc[NT];
#pragma unroll
    for (int i = 0; i < NT; i++) acc[i] = 0.0f;

#pragma unroll
    for (int kk = 0; kk < 4; kk++) {
        int kbyte = kk * 64 + (lane >> 4) * 16;
        bf16x8 a = *(const bf16x8*)((const char*)Xs + (arow * 256) + (kbyte ^ ((arow & 7) << 4)));
#pragma unroll
        for (int ct = 0; ct < NT; ct++) {
            int brow = ct * 16 + (lane & 15);
            bf16x8 b = *(const bf16x8*)((const char*)Ws + (brow * 256) + (kbyte ^ ((brow & 7) << 4)));
            acc[ct] = __builtin_amdgcn_mfma_f32_16x16x32_bf16(a, b, acc[ct], 0, 0, 0);
        }
    }
    // D: col = lane&15, row = (lane>>4)*4 + j   (m89-verified)
    int dcol = lane & 15;
    int drow = wid * 16 + (lane >> 4) * 4;
#pragma unroll
    for (int ct = 0; ct < NT; ct++) {
        int col = ct * 16 + dcol;
#pragma unroll
        for (int j = 0; j < 4; j++) {
            int grow = row0 + drow + j;
            if (grow < N && col < NCOL)
                Hout[(size_t)grow * NCOL + col] = f2bf(acc[ct][j] * dinv[grow]);
        }
    }
}

// ---------------- Aggregation width-128 over pre-scaled bf16 rows ----------------
// out[r] = bf16( relu( (gs[r] + sum_nbr gs[s]) * dinv[r] + bias ) )
__global__ __launch_bounds__(256) void agg128_b(const ushort4* __restrict__ Hp,
                                                const int* __restrict__ rowstart,
                                                const int* __restrict__ srcs,
                                                const float* __restrict__ dinv,
                                                const float* __restrict__ bias,
                                                ushort4* __restrict__ Hout, int N) {
    int r = blockIdx.x * 8 + (threadIdx.x >> 5);
    if (r >= N) return;
    int lane = threadIdx.x & 31;
    int p0 = rowstart[r], p1 = rowstart[r + 1];
    ushort4 sv = Hp[(size_t)r * 32 + lane];
    float a0 = bf2f(sv.x), a1 = bf2f(sv.y), a2 = bf2f(sv.z), a3 = bf2f(sv.w);
    int p = p0;
    for (; p + 8 <= p1; p += 8) {
        int s0 = srcs[p + 0], s1 = srcs[p + 1], s2 = srcs[p + 2], s3 = srcs[p + 3];
        int s4 = srcs[p + 4], s5 = srcs[p + 5], s6 = srcs[p + 6], s7 = srcs[p + 7];
        ushort4 v0 = Hp[(size_t)s0 * 32 + lane];
        ushort4 v1 = Hp[(size_t)s1 * 32 + lane];
        ushort4 v2 = Hp[(size_t)s2 * 32 + lane];
        ushort4 v3 = Hp[(size_t)s3 * 32 + lane];
        ushort4 v4 = Hp[(size_t)s4 * 32 + lane];
        ushort4 v5 = Hp[(size_t)s5 * 32 + lane];
        ushort4 v6 = Hp[(size_t)s6 * 32 + lane];
        ushort4 v7 = Hp[(size_t)s7 * 32 + lane];
        a0 += bf2f(v0.x) + bf2f(v1.x) + bf2f(v2.x) + bf2f(v3.x)
            + bf2f(v4.x) + bf2f(v5.x) + bf2f(v6.x) + bf2f(v7.x);
        a1 += bf2f(v0.y) + bf2f(v1.y) + bf2f(v2.y) + bf2f(v3.y)
            + bf2f(v4.y) + bf2f(v5.y) + bf2f(v6.y) + bf2f(v7.y);
        a2 += bf2f(v0.z) + bf2f(v1.z) + bf2f(v2.z) + bf2f(v3.z)
            + bf2f(v4.z) + bf2f(v5.z) + bf2f(v6.z) + bf2f(v7.z);
        a3 += bf2f(v0.w) + bf2f(v1.w) + bf2f(v2.w) + bf2f(v3.w)
            + bf2f(v4.w) + bf2f(v5.w) + bf2f(v6.w) + bf2f(v7.w);
    }
    for (; p < p1; ++p) {
        int s = srcs[p];
        ushort4 v = Hp[(size_t)s * 32 + lane];
        a0 += bf2f(v.x); a1 += bf2f(v.y); a2 += bf2f(v.z); a3 += bf2f(v.w);
    }
    float dv = dinv[r];
    float o0 = fmaxf(a0 * dv + bias[lane * 4 + 0], 0.f);
    float o1 = fmaxf(a1 * dv + bias[lane * 4 + 1], 0.f);
    float o2 = fmaxf(a2 * dv + bias[lane * 4 + 2], 0.f);
    float o3 = fmaxf(a3 * dv + bias[lane * 4 + 3], 0.f);
    ushort4 o; o.x = f2bf(o0); o.y = f2bf(o1); o.z = f2bf(o2); o.w = f2bf(o3);
    Hout[(size_t)r * 32 + lane] = o;
}

// ---------------- Aggregation width-40 + bias + log_softmax ----------------
// gs: [N][40] bf16 pre-scaled (g*dinv). z = (gs[r] + sum gs[s]) * dinv[r] + b3; out = lsm(z)
__global__ __launch_bounds__(256) void agg40_lsm(const unsigned* __restrict__ Gs,
                                                 const int* __restrict__ rowstart,
                                                 const int* __restrict__ srcs,
                                                 const float* __restrict__ dinv,
                                                 const float* __restrict__ b3,
                                                 float* __restrict__ Out, int N) {
    int r = blockIdx.x * 8 + (threadIdx.x >> 5);
    if (r >= N) return;
    int lane = threadIdx.x & 31;
    bool act = lane < 20;
    int p0 = rowstart[r], p1 = rowstart[r + 1];
    float a0 = 0.f, a1 = 0.f;
    if (act) {
        unsigned v = Gs[(size_t)r * 20 + lane];
        a0 = bf2f((unsigned short)(v & 0xFFFF));
        a1 = bf2f((unsigned short)(v >> 16));
    }
    int p = p0;
    for (; p + 4 <= p1; p += 4) {
        int s0 = srcs[p], s1 = srcs[p + 1], s2 = srcs[p + 2], s3 = srcs[p + 3];
        if (act) {
            unsigned v0 = Gs[(size_t)s0 * 20 + lane];
            unsigned v1 = Gs[(size_t)s1 * 20 + lane];
            unsigned v2 = Gs[(size_t)s2 * 20 + lane];
            unsigned v3 = Gs[(size_t)s3 * 20 + lane];
            a0 += bf2f((unsigned short)(v0 & 0xFFFF)) + bf2f((unsigned short)(v1 & 0xFFFF))
                + bf2f((unsigned short)(v2 & 0xFFFF)) + bf2f((unsigned short)(v3 & 0xFFFF));
            a1 += bf2f((unsigned short)(v0 >> 16)) + bf2f((unsigned short)(v1 >> 16))
                + bf2f((unsigned short)(v2 >> 16)) + bf2f((unsigned short)(v3 >> 16));
        }
    }
    for (; p < p1; ++p) {
        int s = srcs[p];
        if (act) {
            unsigned v = Gs[(size_t)s * 20 + lane];
            a0 += bf2f((unsigned short)(v & 0xFFFF));
            a1 += bf2f((unsigned short)(v >> 16));
        }
    }
    float dv = dinv[r];
    float v0 = act ? (a0 * dv + b3[2 * lane + 0]) : -INFINITY;
    float v1 = act ? (a1 * dv + b3[2 * lane + 1]) : -INFINITY;
    float m = fmaxf(v0, v1);
#pragma unroll
    for (int off = 16; off; off >>= 1) m = fmaxf(m, __shfl_xor(m, off, 32));
    float e = act ? (expf(v0 - m) + expf(v1 - m)) : 0.f;
#pragma unroll
    for (int off = 16; off; off >>= 1) e += __shfl_xor(e, off, 32);
    float lse = m + logf(e);
    if (act) {
        float2 o = make_float2(v0 - lse, v1 - lse);
        *(float2*)&Out[(size_t)r * 40 + 2 * lane] = o;
    }
}

// ---------------- launcher ----------------
extern "C" void kernel_launch(void* const* d_in, const int* in_sizes, int n_in,
                              void* d_out, int out_size, void* d_ws, size_t ws_size,
                              hipStream_t stream) {
    const float* x  = (const float*)d_in[0];
    const int*   ei = (const int*)d_in[1];
    const float* W1 = (const float*)d_in[2];
    const float* b1 = (const float*)d_in[3];
    const float* W2 = (const float*)d_in[4];
    const float* b2 = (const float*)d_in[5];
    const float* W3 = (const float*)d_in[6];
    const float* b3 = (const float*)d_in[7];
    float* out = (float*)d_out;

    const int N = in_sizes[0] / 128;
    const int E = in_sizes[1] / 2;

    auto align = [](size_t v) { return (v + 255) & ~(size_t)255; };
    char* w = (char*)d_ws;
    size_t off = 0;
    unsigned short* bufA = (unsigned short*)(w + off); off += align((size_t)N * 128 * 2);
    unsigned short* bufB = (unsigned short*)(w + off); off += align((size_t)N * 128 * 2);
    unsigned short* gs   = (unsigned short*)(w + off); off += align((size_t)N * 40 * 2);
    unsigned short* W1T  = (unsigned short*)(w + off); off += align(128 * 128 * 2);
    unsigned short* W2T  = (unsigned short*)(w + off); off += align(128 * 128 * 2);
    unsigned short* W3T  = (unsigned short*)(w + off); off += align(40 * 128 * 2);
    int* cnt  = (int*)(w + off);   off += align((size_t)N * 4);
    int* fill = (int*)(w + off);   off += align((size_t)N * 4);
    int* rowstart = (int*)(w + off); off += align((size_t)(N + 1) * 4);
    float* dinv = (float*)(w + off); off += align((size_t)N * 4);
    int* srcs = (int*)(w + off);   off += align((size_t)E * 4);
    int* bsum = (int*)(w + off);   off += align((size_t)1024 * 4);

    hipMemsetAsync(cnt, 0, (size_t)N * 4, stream);
    hipMemsetAsync(fill, 0, (size_t)N * 4, stream);

    TW tw;
    tw.src[0] = W1; tw.dst[0] = W1T; tw.C[0] = 128;
    tw.src[1] = W2; tw.dst[1] = W2T; tw.C[1] = 128;
    tw.src[2] = W3; tw.dst[2] = W3T; tw.C[2] = 40;
    transposeW<<<3, 256, 0, stream>>>(tw);

    int nb = (N + 1023) / 1024;
    count_kernel<<<(E + 255) / 256, 256, 0, stream>>>(ei, cnt, E);
    dinv_kernel<<<(N + 255) / 256, 256, 0, stream>>>(cnt, dinv, N);
    scan1<<<nb, 256, 0, stream>>>(cnt, rowstart, bsum, N);
    scan2<<<1, 64, 0, stream>>>(bsum, nb, rowstart, N, E);
    scan3<<<(N + 255) / 256, 256, 0, stream>>>(rowstart, bsum, N);
    scatter_kernel<<<(E + 255) / 256, 256, 0, stream>>>(ei, rowstart, fill, srcs, E);

    int ggemm = (N + 63) / 64;
    int gagg  = (N + 7) / 8;
    // layer 1
    gemm_mfma<8, 128, true><<<ggemm, 256, 0, stream>>>(x, W1T, dinv, bufA, N);
    agg128_b<<<gagg, 256, 0, stream>>>((const ushort4*)bufA, rowstart, srcs, dinv, b1,
                                       (ushort4*)bufB, N);
    // layer 2
    gemm_mfma<8, 128, false><<<ggemm, 256, 0, stream>>>(bufB, W2T, dinv, bufA, N);
    agg128_b<<<gagg, 256, 0, stream>>>((const ushort4*)bufA, rowstart, srcs, dinv, b2,
                                       (ushort4*)bufB, N);
    // layer 3: GEMM first (width 40), then aggregate + log_softmax
    gemm_mfma<3, 40, false><<<ggemm, 256, 0, stream>>>(bufB, W3T, dinv, gs, N);
    agg40_lsm<<<gagg, 256, 0, stream>>>((const unsigned*)gs, rowstart, srcs, dinv, b3, out, N);
}